// Round 7
// baseline (291.830 us; speedup 1.0000x reference)
//
#include <hip/hip_runtime.h>

#define N_ROWS 32768
#define K_EMB  4096
#define D_DIM  64
#define MARGIN 5e-4f
#define CAND_CAP 16
#define NCHUNKY 16                 // K-chunks for the MFMA passes
#define KT_PER  (K_EMB / NCHUNKY / 16)   // 16x16-code tiles per chunk = 16

// ---- ws layout (float offsets)
#define WS_EE     0
#define WS_BEST   4096      // 32768 x u64 at byte 16384
#define WS_IDX    69632
#define WS_COUNTS 102400
#define WS_DW     106496
#define WS_LOSS   368640
#define WS_N      368641
#define F_BHI     368644    // 4096*64 bf16 = 131072 floats
#define F_BLO     499716
#define F_ROWMIN  630788    // 32768 u32
#define F_CNT     663556    // 32768 u32
#define F_CAND    696324    // 32768*16 i32
#define WS_NEED_BYTES ((size_t)(696324 + 32768 * CAND_CAP) * 4)

// ---- out layout (float offsets)
#define O_ZQ    0
#define O_IDX   2097152
#define O_LOSS  2129920
#define O_EMB   2129921
#define O_CS    2392065
#define O_EMAW  2396161

typedef __attribute__((ext_vector_type(8))) short short8;
typedef __attribute__((ext_vector_type(4))) float f32x4;

__device__ __forceinline__ unsigned short f2bf(float f) {
    unsigned u = __float_as_uint(f);
    unsigned r = (u + 0x7FFFu + ((u >> 16) & 1u)) >> 16;   // RNE
    return (unsigned short)r;
}
__device__ __forceinline__ float bf2f(unsigned short b) {
    return __uint_as_float((unsigned)b << 16);
}
__device__ __forceinline__ unsigned keyf(float f) {
    unsigned u = __float_as_uint(f);
    return (u & 0x80000000u) ? ~u : (u | 0x80000000u);
}
__device__ __forceinline__ float keyinv(unsigned k) {
    unsigned u = (k & 0x80000000u) ? (k ^ 0x80000000u) : ~k;
    return __uint_as_float(u);
}

// ---- prep: ee (exact r1 order) + bf16 hi/lo split of emb
__global__ void k_prep(const float* __restrict__ emb, float* __restrict__ ee,
                       unsigned short* __restrict__ bhi, unsigned short* __restrict__ blo)
{
    int k = blockIdx.x * 256 + threadIdx.x;
    const float4* e4 = (const float4*)(emb + (size_t)k * D_DIM);
    float s0 = 0.f, s1 = 0.f, s2 = 0.f, s3 = 0.f;
    unsigned short* bh = bhi + (size_t)k * D_DIM;
    unsigned short* bl = blo + (size_t)k * D_DIM;
#pragma unroll
    for (int i = 0; i < 16; ++i) {
        float4 v = e4[i];
        s0 = fmaf(v.x, v.x, s0);
        s1 = fmaf(v.y, v.y, s1);
        s2 = fmaf(v.z, v.z, s2);
        s3 = fmaf(v.w, v.w, s3);
        float e[4] = {v.x, v.y, v.z, v.w};
#pragma unroll
        for (int j = 0; j < 4; ++j) {
            unsigned short h = f2bf(e[j]);
            bh[4 * i + j] = h;
            bl[4 * i + j] = f2bf(e[j] - bf2f(h));
        }
    }
    ee[k] = (s0 + s1) + (s2 + s3);
}

// ---- MFMA distance scan.
// PASS 1: per-row min of s1 = ee - 2*dot_hi (hi-only MFMA, approx; error
//         bound |s1-s2| <~ 1.5e-4 << MARGIN).
// PASS 2: collect all k with s2 < rowmin1 + MARGIN (s2 = 3-term hi/lo MFMA).
// Occupancy history: r4/r6 bounds(256,1): granted arch+AGPR regs cap us at
// ~2 waves/SIMD (19% occ) regardless of grid; r5 bounds(256,4): budget 128
// spilled the 64-reg A-frags (WRITE_SIZE 162MB). This round: 32 rows/wave
// (A-frags 32 regs, arch need ~70) + bounds(256,3) (budget 170, no spill,
// >=3 waves/SIMD).
template <int PASS>
__global__ __launch_bounds__(256, 3) void k_mfma_pass(
    const float* __restrict__ z, const unsigned short* __restrict__ bhi,
    const unsigned short* __restrict__ blo, const float* __restrict__ ee,
    unsigned* __restrict__ rowmin, unsigned* __restrict__ cnt, int* __restrict__ cand)
{
    const int tid  = threadIdx.x;
    const int lane = tid & 63, wave = tid >> 6;
    const int lrow = lane & 15, lgrp = lane >> 4;
    const int row0  = blockIdx.x * 128 + wave * 32;       // this wave: 32 rows
    const int kbase = blockIdx.y * (K_EMB / NCHUNKY);     // this chunk: 256 codes

    // A fragments in-register: z rows split to bf16 hi(+lo for PASS 2).
    short8 Ah[2][2], Al[2][2];
#pragma unroll
    for (int s = 0; s < 2; ++s) {
#pragma unroll
        for (int t = 0; t < 2; ++t) {
            const float* zp = z + (size_t)(row0 + s * 16 + lrow) * D_DIM + t * 32 + lgrp * 8;
            float4 f0 = *(const float4*)zp;
            float4 f1 = *(const float4*)(zp + 4);
            float zf[8] = {f0.x, f0.y, f0.z, f0.w, f1.x, f1.y, f1.z, f1.w};
            short8 h, l;
#pragma unroll
            for (int j = 0; j < 8; ++j) {
                unsigned short hb = f2bf(zf[j]);
                h[j] = (short)hb;
                l[j] = (PASS == 2) ? (short)f2bf(zf[j] - bf2f(hb)) : (short)0;
            }
            Ah[s][t] = h;
            if (PASS == 2) Al[s][t] = l;
        }
    }

    float minv[2][4], limit[2][4];
#pragma unroll
    for (int s = 0; s < 2; ++s)
#pragma unroll
        for (int r = 0; r < 4; ++r) {
            minv[s][r] = 3.4e38f;
            if (PASS == 2)
                limit[s][r] = keyinv(rowmin[row0 + s * 16 + lgrp * 4 + r]) + MARGIN;
        }

#pragma unroll 2
    for (int kt = 0; kt < KT_PER; ++kt) {
        const int k0 = kbase + kt * 16;
        const unsigned short* bp = bhi + (size_t)(k0 + lrow) * D_DIM + lgrp * 8;
        short8 Bh0 = *(const short8*)bp, Bh1 = *(const short8*)(bp + 32);
        short8 Bl0, Bl1;
        if (PASS == 2) {
            const unsigned short* lp = blo + (size_t)(k0 + lrow) * D_DIM + lgrp * 8;
            Bl0 = *(const short8*)lp; Bl1 = *(const short8*)(lp + 32);
        }
        float eev = ee[k0 + lrow];
#pragma unroll
        for (int s = 0; s < 2; ++s) {
            f32x4 acc = {0.f, 0.f, 0.f, 0.f};
            acc = __builtin_amdgcn_mfma_f32_16x16x32_bf16(Ah[s][0], Bh0, acc, 0, 0, 0);
            acc = __builtin_amdgcn_mfma_f32_16x16x32_bf16(Ah[s][1], Bh1, acc, 0, 0, 0);
            if (PASS == 2) {
                acc = __builtin_amdgcn_mfma_f32_16x16x32_bf16(Ah[s][0], Bl0, acc, 0, 0, 0);
                acc = __builtin_amdgcn_mfma_f32_16x16x32_bf16(Ah[s][1], Bl1, acc, 0, 0, 0);
                acc = __builtin_amdgcn_mfma_f32_16x16x32_bf16(Al[s][0], Bh0, acc, 0, 0, 0);
                acc = __builtin_amdgcn_mfma_f32_16x16x32_bf16(Al[s][1], Bh1, acc, 0, 0, 0);
            }
#pragma unroll
            for (int r = 0; r < 4; ++r) {
                float sv = fmaf(-2.0f, acc[r], eev);
                if (PASS == 1) {
                    minv[s][r] = fminf(minv[s][r], sv);
                } else {
                    if (sv < limit[s][r]) {
                        int row = row0 + s * 16 + lgrp * 4 + r;
                        unsigned slot = atomicAdd(&cnt[row], 1u);
                        if (slot < (unsigned)CAND_CAP)
                            cand[(size_t)row * CAND_CAP + slot] = k0 + lrow;
                    }
                }
            }
        }
    }

    if (PASS == 1) {
#pragma unroll
        for (int s = 0; s < 2; ++s)
#pragma unroll
            for (int r = 0; r < 4; ++r) {
                float v = minv[s][r];
                v = fminf(v, __shfl_xor(v, 1));
                v = fminf(v, __shfl_xor(v, 2));
                v = fminf(v, __shfl_xor(v, 4));
                v = fminf(v, __shfl_xor(v, 8));
                if (lrow == 0)
                    atomicMin(&rowmin[row0 + s * 16 + lgrp * 4 + r], keyf(v));
            }
    }
}

// ---- exact refine: reference-exact fp32 d for candidates; min + first-index.
__global__ void k_refine(const float* __restrict__ z, const float* __restrict__ emb,
                         const float* __restrict__ ee, const unsigned* __restrict__ cnt,
                         const int* __restrict__ cand, unsigned long long* __restrict__ best)
{
    int row = blockIdx.x * 256 + threadIdx.x;
    const float4* zp = (const float4*)(z + (size_t)row * D_DIM);

    float s0 = 0.f, s1 = 0.f, s2 = 0.f, s3 = 0.f;
#pragma unroll
    for (int i = 0; i < 16; ++i) {
        float4 v = zp[i];
        s0 = fmaf(v.x, v.x, s0);
        s1 = fmaf(v.y, v.y, s1);
        s2 = fmaf(v.z, v.z, s2);
        s3 = fmaf(v.w, v.w, s3);
    }
    const float zz = (s0 + s1) + (s2 + s3);

    int c = (int)cnt[row];
    if (c > CAND_CAP) c = CAND_CAP;
    unsigned long long bk = 0xFFFFFFFFFFFFFFFFull;
    for (int i = 0; i < c; ++i) {
        int k = cand[(size_t)row * CAND_CAP + i];
        const float4* ep = (const float4*)(emb + (size_t)k * D_DIM);
        float d0 = 0.f, d1 = 0.f, d2 = 0.f, d3 = 0.f;
#pragma unroll
        for (int j = 0; j < 16; ++j) {
            float4 zv = zp[j];
            float4 ev = ep[j];
            d0 = fmaf(zv.x, ev.x, d0);
            d1 = fmaf(zv.y, ev.y, d1);
            d2 = fmaf(zv.z, ev.z, d2);
            d3 = fmaf(zv.w, ev.w, d3);
        }
        float dot = (d0 + d1) + (d2 + d3);
        float dv  = fmaf(-2.0f, dot, zz + ee[k]);   // exact r1-verified formula
        unsigned long long key =
            ((unsigned long long)__float_as_uint(dv) << 32) | (unsigned)k;
        bk = (key < bk) ? key : bk;
    }
    best[row] = bk;
}

// ---- fallback argmin (exact r2 kernel, proven passing) ----
#define NCHUNK_FB 16
#define KC_FB     (K_EMB / NCHUNK_FB)
__global__ __launch_bounds__(256) void k_argmin_fb(
    const float* __restrict__ z, const float* __restrict__ emb,
    const float* __restrict__ ee, unsigned long long* __restrict__ best)
{
    const int n  = blockIdx.x * 256 + threadIdx.x;
    const int c  = blockIdx.y;
    const int k0 = c * KC_FB;

    float4 zr[16];
    const float4* zp = (const float4*)(z + (size_t)n * D_DIM);
#pragma unroll
    for (int i = 0; i < 16; ++i) zr[i] = zp[i];

    float s0 = 0.f, s1 = 0.f, s2 = 0.f, s3 = 0.f;
#pragma unroll
    for (int i = 0; i < 16; ++i) {
        s0 = fmaf(zr[i].x, zr[i].x, s0);
        s1 = fmaf(zr[i].y, zr[i].y, s1);
        s2 = fmaf(zr[i].z, zr[i].z, s2);
        s3 = fmaf(zr[i].w, zr[i].w, s3);
    }
    const float zz = (s0 + s1) + (s2 + s3);

    const float4* ep  = (const float4*)(emb + (size_t)k0 * D_DIM);
    const float*  eep = ee + k0;

    float bestv = 3.4e38f;
    int   bi    = 0;
#pragma unroll 2
    for (int kk = 0; kk < KC_FB; ++kk) {
        float d0 = 0.f, d1 = 0.f, d2 = 0.f, d3 = 0.f;
#pragma unroll
        for (int i = 0; i < 16; ++i) {
            float4 ev = ep[kk * 16 + i];
            d0 = fmaf(zr[i].x, ev.x, d0);
            d1 = fmaf(zr[i].y, ev.y, d1);
            d2 = fmaf(zr[i].z, ev.z, d2);
            d3 = fmaf(zr[i].w, ev.w, d3);
        }
        float dot = (d0 + d1) + (d2 + d3);
        float dv = fmaf(-2.0f, dot, zz + eep[kk]);
        if (dv < bestv) { bestv = dv; bi = kk; }
    }
    unsigned long long key =
        ((unsigned long long)__float_as_uint(bestv) << 32) | (unsigned)(k0 + bi);
    atomicMin(best + n, key);
}

// ---- shared epilogue kernels (verified r1-r6) ----
__global__ void k_finish(const unsigned long long* __restrict__ best,
                         int* __restrict__ idxbuf, float* __restrict__ oidx)
{
    int n = blockIdx.x * 256 + threadIdx.x;
    int bi = (int)(best[n] & 0xFFFFFFFFull);
    idxbuf[n] = bi;
    oidx[n]   = (float)bi;
}

__global__ void k_scatter(const float* __restrict__ z, const float* __restrict__ emb,
                          const int* __restrict__ idxbuf, float* __restrict__ out_zq,
                          float* __restrict__ counts, float* __restrict__ dw,
                          float* __restrict__ lossacc)
{
    int t = blockIdx.x * 256 + threadIdx.x;
    float acc = 0.f;
#pragma unroll
    for (int i = 0; i < 16; ++i) {
        int e = t + i * 131072;
        int nrow = e >> 6, d = e & 63;
        int k = idxbuf[nrow];
        float zv  = z[e];
        float evv = emb[(size_t)k * D_DIM + d];
        out_zq[e] = zv + (evv - zv);
        float diff = zv - evv;
        acc = fmaf(diff, diff, acc);
        atomicAdd(&dw[(size_t)k * D_DIM + d], zv);
        if (d == 0) atomicAdd(&counts[k], 1.0f);
    }
    __shared__ float red[256];
    red[threadIdx.x] = acc;
    __syncthreads();
    for (int s = 128; s > 0; s >>= 1) {
        if (threadIdx.x < s) red[threadIdx.x] += red[threadIdx.x + s];
        __syncthreads();
    }
    if (threadIdx.x == 0) atomicAdd(lossacc, red[0]);
}

__global__ void k_stats(const float* __restrict__ ema_cs, const float* __restrict__ counts,
                        const float* __restrict__ lossacc, float* __restrict__ out_cs,
                        float* __restrict__ out_loss, float* __restrict__ ws_n)
{
    __shared__ float red[256];
    float local = 0.f;
    for (int k = threadIdx.x; k < K_EMB; k += 256) {
        float v = 0.99f * ema_cs[k] + 0.01f * counts[k];
        out_cs[k] = v;
        local += v;
    }
    red[threadIdx.x] = local;
    __syncthreads();
    for (int s = 128; s > 0; s >>= 1) {
        if (threadIdx.x < s) red[threadIdx.x] += red[threadIdx.x + s];
        __syncthreads();
    }
    if (threadIdx.x == 0) {
        ws_n[0] = red[0];
        out_loss[0] = 0.25f * (lossacc[0] / 2097152.0f);
    }
}

__global__ void k_emb(const float* __restrict__ ema_w, const float* __restrict__ dw,
                      const float* __restrict__ out_cs, const float* __restrict__ ws_n,
                      float* __restrict__ out_emb, float* __restrict__ out_emaw)
{
    int e = blockIdx.x * 256 + threadIdx.x;
    int k = e >> 6;
    float nv = ws_n[0];
    float w  = 0.99f * ema_w[e] + 0.01f * dw[e];
    out_emaw[e] = w;
    float cs = (out_cs[k] + 1e-5f) / (nv + 0.04096f) * nv;
    out_emb[e] = w / cs;
}

extern "C" void kernel_launch(void* const* d_in, const int* in_sizes, int n_in,
                              void* d_out, int out_size, void* d_ws, size_t ws_size,
                              hipStream_t stream)
{
    const float* z      = (const float*)d_in[0];
    const float* emb    = (const float*)d_in[1];
    const float* ema_cs = (const float*)d_in[2];
    const float* ema_w  = (const float*)d_in[3];

    float* out   = (float*)d_out;
    float* o_zq  = out + O_ZQ;
    float* o_idx = out + O_IDX;
    float* o_ls  = out + O_LOSS;
    float* o_em  = out + O_EMB;
    float* o_cs  = out + O_CS;
    float* o_ew  = out + O_EMAW;

    float* w      = (float*)d_ws;
    float* ee     = w + WS_EE;
    unsigned long long* best = (unsigned long long*)(w + WS_BEST);
    int*   idxbuf = (int*)(w + WS_IDX);
    float* counts = w + WS_COUNTS;
    float* dw     = w + WS_DW;
    float* lossa  = w + WS_LOSS;
    float* ws_n   = w + WS_N;

    hipMemsetAsync((char*)d_ws + (size_t)WS_BEST * 4, 0xFF, (size_t)N_ROWS * 8, stream);
    hipMemsetAsync((char*)d_ws + (size_t)WS_COUNTS * 4, 0,
                   (size_t)(WS_N + 1 - WS_COUNTS) * 4, stream);

    if (ws_size >= WS_NEED_BYTES) {
        unsigned short* bhi = (unsigned short*)(w + F_BHI);
        unsigned short* blo = (unsigned short*)(w + F_BLO);
        unsigned* rowmin    = (unsigned*)(w + F_ROWMIN);
        unsigned* cnt       = (unsigned*)(w + F_CNT);
        int*      cand      = (int*)(w + F_CAND);

        hipMemsetAsync((char*)d_ws + (size_t)F_ROWMIN * 4, 0xFF, (size_t)N_ROWS * 4, stream);
        hipMemsetAsync((char*)d_ws + (size_t)F_CNT * 4, 0, (size_t)N_ROWS * 4, stream);

        k_prep<<<K_EMB / 256, 256, 0, stream>>>(emb, ee, bhi, blo);
        k_mfma_pass<1><<<dim3(N_ROWS / 128, NCHUNKY), 256, 0, stream>>>(z, bhi, blo, ee,
                                                                        rowmin, cnt, cand);
        k_mfma_pass<2><<<dim3(N_ROWS / 128, NCHUNKY), 256, 0, stream>>>(z, bhi, blo, ee,
                                                                        rowmin, cnt, cand);
        k_refine<<<N_ROWS / 256, 256, 0, stream>>>(z, emb, ee, cnt, cand, best);
    } else {
        k_prep<<<K_EMB / 256, 256, 0, stream>>>(emb, ee,
                                                (unsigned short*)(w + WS_EE),
                                                (unsigned short*)(w + WS_EE));
        k_argmin_fb<<<dim3(N_ROWS / 256, NCHUNK_FB), 256, 0, stream>>>(z, emb, ee, best);
    }

    k_finish<<<N_ROWS / 256, 256, 0, stream>>>(best, idxbuf, o_idx);
    k_scatter<<<512, 256, 0, stream>>>(z, emb, idxbuf, o_zq, counts, dw, lossa);
    k_stats<<<1, 256, 0, stream>>>(ema_cs, counts, lossa, o_cs, o_ls, ws_n);
    k_emb<<<(K_EMB * D_DIM) / 256, 256, 0, stream>>>(ema_w, dw, o_cs, ws_n, o_em, o_ew);
}

// Round 8
// 185.155 us; speedup vs baseline: 1.5761x; 1.5761x over previous
//
#include <hip/hip_runtime.h>

#define N_ROWS 32768
#define K_EMB  4096
#define D_DIM  64
#define MARGIN 5e-4f
#define CAND_CAP 16
#define NCHUNKY 16                 // K-chunks for the MFMA passes (256 codes each)

// ---- ws layout (float offsets)
#define WS_EE     0
#define WS_BEST   4096      // 32768 x u64 at byte 16384
#define WS_IDX    69632
#define WS_COUNTS 102400
#define WS_DW     106496
#define WS_LOSS   368640
#define WS_N      368641
#define F_BHI     368644    // 4096*64 bf16 = 131072 shorts = 65536 floats
#define F_BLO     499716    // (unused since r8; kept so layout/NEED_BYTES is stable)
#define F_ROWMIN  630788    // 32768 u32
#define F_CNT     663556    // 32768 u32
#define F_CAND    696324    // 32768*16 i32
#define WS_NEED_BYTES ((size_t)(696324 + 32768 * CAND_CAP) * 4)

// ---- out layout (float offsets)
#define O_ZQ    0
#define O_IDX   2097152
#define O_LOSS  2129920
#define O_EMB   2129921
#define O_CS    2392065
#define O_EMAW  2396161

typedef __attribute__((ext_vector_type(8))) short short8;
typedef __attribute__((ext_vector_type(4))) float f32x4;

__device__ __forceinline__ unsigned short f2bf(float f) {
    unsigned u = __float_as_uint(f);
    unsigned r = (u + 0x7FFFu + ((u >> 16) & 1u)) >> 16;   // RNE
    return (unsigned short)r;
}
__device__ __forceinline__ unsigned keyf(float f) {
    unsigned u = __float_as_uint(f);
    return (u & 0x80000000u) ? ~u : (u | 0x80000000u);
}
__device__ __forceinline__ float keyinv(unsigned k) {
    unsigned u = (k & 0x80000000u) ? (k ^ 0x80000000u) : ~k;
    return __uint_as_float(u);
}

// ---- ee only (exact r1 order) — used by the fallback path
__global__ void k_ee(const float* __restrict__ emb, float* __restrict__ ee) {
    int k = blockIdx.x * 256 + threadIdx.x;
    const float4* e4 = (const float4*)(emb + (size_t)k * D_DIM);
    float s0 = 0.f, s1 = 0.f, s2 = 0.f, s3 = 0.f;
#pragma unroll
    for (int i = 0; i < 16; ++i) {
        float4 v = e4[i];
        s0 = fmaf(v.x, v.x, s0);
        s1 = fmaf(v.y, v.y, s1);
        s2 = fmaf(v.z, v.z, s2);
        s3 = fmaf(v.w, v.w, s3);
    }
    ee[k] = (s0 + s1) + (s2 + s3);
}

// ---- prep: ee (exact r1 order) + bf16 hi split of emb (lo no longer needed:
// both MFMA passes are hi-only; exactness is restored in k_refine)
__global__ void k_prep(const float* __restrict__ emb, float* __restrict__ ee,
                       unsigned short* __restrict__ bhi)
{
    int k = blockIdx.x * 256 + threadIdx.x;
    const float4* e4 = (const float4*)(emb + (size_t)k * D_DIM);
    float s0 = 0.f, s1 = 0.f, s2 = 0.f, s3 = 0.f;
    unsigned short* bh = bhi + (size_t)k * D_DIM;
#pragma unroll
    for (int i = 0; i < 16; ++i) {
        float4 v = e4[i];
        s0 = fmaf(v.x, v.x, s0);
        s1 = fmaf(v.y, v.y, s1);
        s2 = fmaf(v.z, v.z, s2);
        s3 = fmaf(v.w, v.w, s3);
        bh[4 * i + 0] = f2bf(v.x);
        bh[4 * i + 1] = f2bf(v.y);
        bh[4 * i + 2] = f2bf(v.z);
        bh[4 * i + 3] = f2bf(v.w);
    }
    ee[k] = (s0 + s1) + (s2 + s3);
}

// ---- hi-only MFMA distance scan.
// PASS 1: per-row min of s_hi = ee - 2*dot_hi.
// PASS 2: collect all k with s_hi < rowmin + MARGIN.
// Correctness: |s_hi - s_exact| <= 2*Sum|z||e|*2^-8 ~ 5.6e-5 (2.2e-4 @ 8sigma);
// true argmin k* has s_hi(k*) <= rowmin_hi + 2*err < MARGIN. k_refine then
// evaluates the reference-exact fp32 formula on candidates -> bit-exact pick.
// AI history: r7 (4 MFMA / 36B/lane) latency-exposed at any occupancy; this
// round 64 rows/wave x 32 codes/iter = 16 MFMA (~310 SIMD-cyc) per 72B/lane.
template <int PASS>
__global__ __launch_bounds__(256, 3) void k_mfma_pass(
    const float* __restrict__ z, const unsigned short* __restrict__ bhi,
    const float* __restrict__ ee,
    unsigned* __restrict__ rowmin, unsigned* __restrict__ cnt, int* __restrict__ cand)
{
    const int tid  = threadIdx.x;
    const int lane = tid & 63, wave = tid >> 6;
    const int lrow = lane & 15, lgrp = lane >> 4;
    const int row0  = blockIdx.x * 256 + wave * 64;   // this wave: 64 rows
    const int kbase = blockIdx.y * (K_EMB / NCHUNKY); // this chunk: 256 codes

    // A fragments (hi only): 4 row-subtiles x 2 K-halves = 32 VGPRs.
    short8 Ah[4][2];
#pragma unroll
    for (int s = 0; s < 4; ++s) {
#pragma unroll
        for (int t = 0; t < 2; ++t) {
            const float* zp = z + (size_t)(row0 + s * 16 + lrow) * D_DIM + t * 32 + lgrp * 8;
            float4 f0 = *(const float4*)zp;
            float4 f1 = *(const float4*)(zp + 4);
            float zf[8] = {f0.x, f0.y, f0.z, f0.w, f1.x, f1.y, f1.z, f1.w};
            short8 h;
#pragma unroll
            for (int j = 0; j < 8; ++j) h[j] = (short)f2bf(zf[j]);
            Ah[s][t] = h;
        }
    }

    float track[4][4];   // PASS1: running min; PASS2: limit
#pragma unroll
    for (int s = 0; s < 4; ++s)
#pragma unroll
        for (int r = 0; r < 4; ++r) {
            track[s][r] = (PASS == 1)
                ? 3.4e38f
                : keyinv(rowmin[row0 + s * 16 + lgrp * 4 + r]) + MARGIN;
        }

#pragma unroll 2
    for (int kt = 0; kt < (K_EMB / NCHUNKY) / 32; ++kt) {   // 8 iters x 32 codes
        const int k0 = kbase + kt * 32;
        short8 B0[2], B1[2];
        float  ev[2];
#pragma unroll
        for (int u = 0; u < 2; ++u) {
            const unsigned short* bp = bhi + (size_t)(k0 + u * 16 + lrow) * D_DIM + lgrp * 8;
            B0[u] = *(const short8*)bp;
            B1[u] = *(const short8*)(bp + 32);
            ev[u] = ee[k0 + u * 16 + lrow];
        }
#pragma unroll
        for (int s = 0; s < 4; ++s) {
#pragma unroll
            for (int u = 0; u < 2; ++u) {
                f32x4 acc = {0.f, 0.f, 0.f, 0.f};
                acc = __builtin_amdgcn_mfma_f32_16x16x32_bf16(Ah[s][0], B0[u], acc, 0, 0, 0);
                acc = __builtin_amdgcn_mfma_f32_16x16x32_bf16(Ah[s][1], B1[u], acc, 0, 0, 0);
#pragma unroll
                for (int r = 0; r < 4; ++r) {
                    float sv = fmaf(-2.0f, acc[r], ev[u]);
                    if (PASS == 1) {
                        track[s][r] = fminf(track[s][r], sv);
                    } else {
                        if (sv < track[s][r]) {
                            int row = row0 + s * 16 + lgrp * 4 + r;
                            unsigned slot = atomicAdd(&cnt[row], 1u);
                            if (slot < (unsigned)CAND_CAP)
                                cand[(size_t)row * CAND_CAP + slot] = k0 + u * 16 + lrow;
                        }
                    }
                }
            }
        }
    }

    if (PASS == 1) {
#pragma unroll
        for (int s = 0; s < 4; ++s)
#pragma unroll
            for (int r = 0; r < 4; ++r) {
                float v = track[s][r];
                v = fminf(v, __shfl_xor(v, 1));
                v = fminf(v, __shfl_xor(v, 2));
                v = fminf(v, __shfl_xor(v, 4));
                v = fminf(v, __shfl_xor(v, 8));
                if (lrow == 0)
                    atomicMin(&rowmin[row0 + s * 16 + lgrp * 4 + r], keyf(v));
            }
    }
}

// ---- exact refine: reference-exact fp32 d for candidates; min + first-index.
__global__ void k_refine(const float* __restrict__ z, const float* __restrict__ emb,
                         const float* __restrict__ ee, const unsigned* __restrict__ cnt,
                         const int* __restrict__ cand, unsigned long long* __restrict__ best)
{
    int row = blockIdx.x * 256 + threadIdx.x;
    const float4* zp = (const float4*)(z + (size_t)row * D_DIM);

    float s0 = 0.f, s1 = 0.f, s2 = 0.f, s3 = 0.f;
#pragma unroll
    for (int i = 0; i < 16; ++i) {
        float4 v = zp[i];
        s0 = fmaf(v.x, v.x, s0);
        s1 = fmaf(v.y, v.y, s1);
        s2 = fmaf(v.z, v.z, s2);
        s3 = fmaf(v.w, v.w, s3);
    }
    const float zz = (s0 + s1) + (s2 + s3);

    int c = (int)cnt[row];
    if (c > CAND_CAP) c = CAND_CAP;
    unsigned long long bk = 0xFFFFFFFFFFFFFFFFull;
    for (int i = 0; i < c; ++i) {
        int k = cand[(size_t)row * CAND_CAP + i];
        const float4* ep = (const float4*)(emb + (size_t)k * D_DIM);
        float d0 = 0.f, d1 = 0.f, d2 = 0.f, d3 = 0.f;
#pragma unroll
        for (int j = 0; j < 16; ++j) {
            float4 zv = zp[j];
            float4 ev = ep[j];
            d0 = fmaf(zv.x, ev.x, d0);
            d1 = fmaf(zv.y, ev.y, d1);
            d2 = fmaf(zv.z, ev.z, d2);
            d3 = fmaf(zv.w, ev.w, d3);
        }
        float dot = (d0 + d1) + (d2 + d3);
        float dv  = fmaf(-2.0f, dot, zz + ee[k]);   // exact r1-verified formula
        unsigned long long key =
            ((unsigned long long)__float_as_uint(dv) << 32) | (unsigned)k;
        bk = (key < bk) ? key : bk;
    }
    best[row] = bk;
}

// ---- fallback argmin (exact r2 kernel, proven passing) ----
#define NCHUNK_FB 16
#define KC_FB     (K_EMB / NCHUNK_FB)
__global__ __launch_bounds__(256) void k_argmin_fb(
    const float* __restrict__ z, const float* __restrict__ emb,
    const float* __restrict__ ee, unsigned long long* __restrict__ best)
{
    const int n  = blockIdx.x * 256 + threadIdx.x;
    const int c  = blockIdx.y;
    const int k0 = c * KC_FB;

    float4 zr[16];
    const float4* zp = (const float4*)(z + (size_t)n * D_DIM);
#pragma unroll
    for (int i = 0; i < 16; ++i) zr[i] = zp[i];

    float s0 = 0.f, s1 = 0.f, s2 = 0.f, s3 = 0.f;
#pragma unroll
    for (int i = 0; i < 16; ++i) {
        s0 = fmaf(zr[i].x, zr[i].x, s0);
        s1 = fmaf(zr[i].y, zr[i].y, s1);
        s2 = fmaf(zr[i].z, zr[i].z, s2);
        s3 = fmaf(zr[i].w, zr[i].w, s3);
    }
    const float zz = (s0 + s1) + (s2 + s3);

    const float4* ep  = (const float4*)(emb + (size_t)k0 * D_DIM);
    const float*  eep = ee + k0;

    float bestv = 3.4e38f;
    int   bi    = 0;
#pragma unroll 2
    for (int kk = 0; kk < KC_FB; ++kk) {
        float d0 = 0.f, d1 = 0.f, d2 = 0.f, d3 = 0.f;
#pragma unroll
        for (int i = 0; i < 16; ++i) {
            float4 ev = ep[kk * 16 + i];
            d0 = fmaf(zr[i].x, ev.x, d0);
            d1 = fmaf(zr[i].y, ev.y, d1);
            d2 = fmaf(zr[i].z, ev.z, d2);
            d3 = fmaf(zr[i].w, ev.w, d3);
        }
        float dot = (d0 + d1) + (d2 + d3);
        float dv = fmaf(-2.0f, dot, zz + eep[kk]);
        if (dv < bestv) { bestv = dv; bi = kk; }
    }
    unsigned long long key =
        ((unsigned long long)__float_as_uint(bestv) << 32) | (unsigned)(k0 + bi);
    atomicMin(best + n, key);
}

// ---- shared epilogue kernels (verified r1-r7) ----
__global__ void k_finish(const unsigned long long* __restrict__ best,
                         int* __restrict__ idxbuf, float* __restrict__ oidx)
{
    int n = blockIdx.x * 256 + threadIdx.x;
    int bi = (int)(best[n] & 0xFFFFFFFFull);
    idxbuf[n] = bi;
    oidx[n]   = (float)bi;
}

__global__ void k_scatter(const float* __restrict__ z, const float* __restrict__ emb,
                          const int* __restrict__ idxbuf, float* __restrict__ out_zq,
                          float* __restrict__ counts, float* __restrict__ dw,
                          float* __restrict__ lossacc)
{
    int t = blockIdx.x * 256 + threadIdx.x;
    float acc = 0.f;
#pragma unroll
    for (int i = 0; i < 16; ++i) {
        int e = t + i * 131072;
        int nrow = e >> 6, d = e & 63;
        int k = idxbuf[nrow];
        float zv  = z[e];
        float evv = emb[(size_t)k * D_DIM + d];
        out_zq[e] = zv + (evv - zv);
        float diff = zv - evv;
        acc = fmaf(diff, diff, acc);
        atomicAdd(&dw[(size_t)k * D_DIM + d], zv);
        if (d == 0) atomicAdd(&counts[k], 1.0f);
    }
    __shared__ float red[256];
    red[threadIdx.x] = acc;
    __syncthreads();
    for (int s = 128; s > 0; s >>= 1) {
        if (threadIdx.x < s) red[threadIdx.x] += red[threadIdx.x + s];
        __syncthreads();
    }
    if (threadIdx.x == 0) atomicAdd(lossacc, red[0]);
}

__global__ void k_stats(const float* __restrict__ ema_cs, const float* __restrict__ counts,
                        const float* __restrict__ lossacc, float* __restrict__ out_cs,
                        float* __restrict__ out_loss, float* __restrict__ ws_n)
{
    __shared__ float red[256];
    float local = 0.f;
    for (int k = threadIdx.x; k < K_EMB; k += 256) {
        float v = 0.99f * ema_cs[k] + 0.01f * counts[k];
        out_cs[k] = v;
        local += v;
    }
    red[threadIdx.x] = local;
    __syncthreads();
    for (int s = 128; s > 0; s >>= 1) {
        if (threadIdx.x < s) red[threadIdx.x] += red[threadIdx.x + s];
        __syncthreads();
    }
    if (threadIdx.x == 0) {
        ws_n[0] = red[0];
        out_loss[0] = 0.25f * (lossacc[0] / 2097152.0f);
    }
}

__global__ void k_emb(const float* __restrict__ ema_w, const float* __restrict__ dw,
                      const float* __restrict__ out_cs, const float* __restrict__ ws_n,
                      float* __restrict__ out_emb, float* __restrict__ out_emaw)
{
    int e = blockIdx.x * 256 + threadIdx.x;
    int k = e >> 6;
    float nv = ws_n[0];
    float w  = 0.99f * ema_w[e] + 0.01f * dw[e];
    out_emaw[e] = w;
    float cs = (out_cs[k] + 1e-5f) / (nv + 0.04096f) * nv;
    out_emb[e] = w / cs;
}

extern "C" void kernel_launch(void* const* d_in, const int* in_sizes, int n_in,
                              void* d_out, int out_size, void* d_ws, size_t ws_size,
                              hipStream_t stream)
{
    const float* z      = (const float*)d_in[0];
    const float* emb    = (const float*)d_in[1];
    const float* ema_cs = (const float*)d_in[2];
    const float* ema_w  = (const float*)d_in[3];

    float* out   = (float*)d_out;
    float* o_zq  = out + O_ZQ;
    float* o_idx = out + O_IDX;
    float* o_ls  = out + O_LOSS;
    float* o_em  = out + O_EMB;
    float* o_cs  = out + O_CS;
    float* o_ew  = out + O_EMAW;

    float* w      = (float*)d_ws;
    float* ee     = w + WS_EE;
    unsigned long long* best = (unsigned long long*)(w + WS_BEST);
    int*   idxbuf = (int*)(w + WS_IDX);
    float* counts = w + WS_COUNTS;
    float* dw     = w + WS_DW;
    float* lossa  = w + WS_LOSS;
    float* ws_n   = w + WS_N;

    hipMemsetAsync((char*)d_ws + (size_t)WS_BEST * 4, 0xFF, (size_t)N_ROWS * 8, stream);
    hipMemsetAsync((char*)d_ws + (size_t)WS_COUNTS * 4, 0,
                   (size_t)(WS_N + 1 - WS_COUNTS) * 4, stream);

    if (ws_size >= WS_NEED_BYTES) {
        unsigned short* bhi = (unsigned short*)(w + F_BHI);
        unsigned* rowmin    = (unsigned*)(w + F_ROWMIN);
        unsigned* cnt       = (unsigned*)(w + F_CNT);
        int*      cand      = (int*)(w + F_CAND);

        hipMemsetAsync((char*)d_ws + (size_t)F_ROWMIN * 4, 0xFF, (size_t)N_ROWS * 4, stream);
        hipMemsetAsync((char*)d_ws + (size_t)F_CNT * 4, 0, (size_t)N_ROWS * 4, stream);

        k_prep<<<K_EMB / 256, 256, 0, stream>>>(emb, ee, bhi);
        k_mfma_pass<1><<<dim3(N_ROWS / 256, NCHUNKY), 256, 0, stream>>>(z, bhi, ee,
                                                                        rowmin, cnt, cand);
        k_mfma_pass<2><<<dim3(N_ROWS / 256, NCHUNKY), 256, 0, stream>>>(z, bhi, ee,
                                                                        rowmin, cnt, cand);
        k_refine<<<N_ROWS / 256, 256, 0, stream>>>(z, emb, ee, cnt, cand, best);
    } else {
        k_ee<<<K_EMB / 256, 256, 0, stream>>>(emb, ee);
        k_argmin_fb<<<dim3(N_ROWS / 256, NCHUNK_FB), 256, 0, stream>>>(z, emb, ee, best);
    }

    k_finish<<<N_ROWS / 256, 256, 0, stream>>>(best, idxbuf, o_idx);
    k_scatter<<<512, 256, 0, stream>>>(z, emb, idxbuf, o_zq, counts, dw, lossa);
    k_stats<<<1, 256, 0, stream>>>(ema_cs, counts, lossa, o_cs, o_ls, ws_n);
    k_emb<<<(K_EMB * D_DIM) / 256, 256, 0, stream>>>(ema_w, dw, o_cs, ws_n, o_em, o_ew);
}

// Round 9
// 160.463 us; speedup vs baseline: 1.8187x; 1.1539x over previous
//
#include <hip/hip_runtime.h>

#define N_ROWS 32768
#define K_EMB  4096
#define D_DIM  64
#define MARGIN 5e-4f
#define CAND_CAP 16
#define NCHUNKY 16                 // K-chunks for the MFMA passes (256 codes each)
#define KC_CH   (K_EMB / NCHUNKY)  // 256 codes per chunk

// ---- ws layout (float offsets)
#define WS_EE     0
#define WS_BEST   4096      // 32768 x u64 at byte 16384
#define WS_IDX    69632
#define WS_COUNTS 102400
#define WS_DW     106496
#define WS_LOSS   368640
#define WS_N      368641
#define F_BHI     368644    // 4096*64 bf16 = 131072 shorts = 65536 floats
#define F_BLO     499716    // (unused; kept so layout/NEED_BYTES is stable)
#define F_ROWMIN  630788    // 32768 u32
#define F_CNT     663556    // 32768 u32
#define F_CAND    696324    // 32768*16 i32
#define WS_NEED_BYTES ((size_t)(696324 + 32768 * CAND_CAP) * 4)

// ---- out layout (float offsets)
#define O_ZQ    0
#define O_IDX   2097152
#define O_LOSS  2129920
#define O_EMB   2129921
#define O_CS    2392065
#define O_EMAW  2396161

typedef __attribute__((ext_vector_type(8))) short short8;
typedef __attribute__((ext_vector_type(4))) float f32x4;

__device__ __forceinline__ unsigned short f2bf(float f) {
    unsigned u = __float_as_uint(f);
    unsigned r = (u + 0x7FFFu + ((u >> 16) & 1u)) >> 16;   // RNE
    return (unsigned short)r;
}
__device__ __forceinline__ unsigned keyf(float f) {
    unsigned u = __float_as_uint(f);
    return (u & 0x80000000u) ? ~u : (u | 0x80000000u);
}
__device__ __forceinline__ float keyinv(unsigned k) {
    unsigned u = (k & 0x80000000u) ? (k ^ 0x80000000u) : ~k;
    return __uint_as_float(u);
}

// ---- ee only (exact r1 order) — used by the fallback path
__global__ void k_ee(const float* __restrict__ emb, float* __restrict__ ee) {
    int k = blockIdx.x * 256 + threadIdx.x;
    const float4* e4 = (const float4*)(emb + (size_t)k * D_DIM);
    float s0 = 0.f, s1 = 0.f, s2 = 0.f, s3 = 0.f;
#pragma unroll
    for (int i = 0; i < 16; ++i) {
        float4 v = e4[i];
        s0 = fmaf(v.x, v.x, s0);
        s1 = fmaf(v.y, v.y, s1);
        s2 = fmaf(v.z, v.z, s2);
        s3 = fmaf(v.w, v.w, s3);
    }
    ee[k] = (s0 + s1) + (s2 + s3);
}

// ---- prep: ee (exact r1 order) + bf16 hi split of emb
__global__ void k_prep(const float* __restrict__ emb, float* __restrict__ ee,
                       unsigned short* __restrict__ bhi)
{
    int k = blockIdx.x * 256 + threadIdx.x;
    const float4* e4 = (const float4*)(emb + (size_t)k * D_DIM);
    float s0 = 0.f, s1 = 0.f, s2 = 0.f, s3 = 0.f;
    unsigned short* bh = bhi + (size_t)k * D_DIM;
#pragma unroll
    for (int i = 0; i < 16; ++i) {
        float4 v = e4[i];
        s0 = fmaf(v.x, v.x, s0);
        s1 = fmaf(v.y, v.y, s1);
        s2 = fmaf(v.z, v.z, s2);
        s3 = fmaf(v.w, v.w, s3);
        bh[4 * i + 0] = f2bf(v.x);
        bh[4 * i + 1] = f2bf(v.y);
        bh[4 * i + 2] = f2bf(v.z);
        bh[4 * i + 3] = f2bf(v.w);
    }
    ee[k] = (s0 + s1) + (s2 + s3);
}

// ---- hi-only MFMA distance scan, LDS-staged B.
// r8 post-mortem: duration tracked #global-load-instructions (~400cyc each,
// zero overlap). Fix: stage the block's 32KB B-chunk + (-ee/2) in LDS once;
// the K-loop then issues ONLY ds_read (XOR-swizzled: slot' = slot^(c&7), so
// the stride-128B b128 reads are <=2-way bank conflicts).
// VALU diet: acc is initialized to -ee/2, so s = -2*acc and PASS1 tracking is
// a single fmax per element; *(-2) and *(-0.5) are exact, candidate set and
// refine selection unchanged (refine recomputes the reference-exact formula).
template <int PASS>
__global__ __launch_bounds__(256, 3) void k_mfma_pass(
    const float* __restrict__ z, const unsigned short* __restrict__ bhi,
    const float* __restrict__ ee,
    unsigned* __restrict__ rowmin, unsigned* __restrict__ cnt, int* __restrict__ cand)
{
    __shared__ unsigned short lds_b[KC_CH * 64];  // 32 KB, swizzled
    __shared__ float lds_e2[KC_CH];               // -ee/2, 1 KB

    const int tid  = threadIdx.x;
    const int lane = tid & 63, wave = tid >> 6;
    const int lrow = lane & 15, lgrp = lane >> 4;
    const int row0  = blockIdx.x * 256 + wave * 64;   // this wave: 64 rows
    const int kbase = blockIdx.y * KC_CH;             // this chunk: 256 codes

    // ---- stage B chunk: coalesced global (thread t reads 8x16B at stride 4KB),
    // swizzled ds_write: chunk byte (t*16 + j*4096) -> code c=(t>>3)+j*32, slot s=t&7.
    {
        const short8* gsrc = (const short8*)(bhi + (size_t)kbase * D_DIM);
        short8 v[8];
#pragma unroll
        for (int j = 0; j < 8; ++j) v[j] = gsrc[tid + j * 256];
        const int s_slot = tid & 7, c0 = tid >> 3;
#pragma unroll
        for (int j = 0; j < 8; ++j) {
            int c = c0 + j * 32;
            *(short8*)&lds_b[c * 64 + ((s_slot ^ (c & 7)) << 3)] = v[j];
        }
        if (tid < KC_CH) lds_e2[tid] = -0.5f * ee[kbase + tid];
    }

    // ---- A fragments (hi only): 4 row-subtiles x 2 K-halves = 32 VGPRs.
    short8 Ah[4][2];
#pragma unroll
    for (int s = 0; s < 4; ++s) {
#pragma unroll
        for (int t = 0; t < 2; ++t) {
            const float* zp = z + (size_t)(row0 + s * 16 + lrow) * D_DIM + t * 32 + lgrp * 8;
            float4 f0 = *(const float4*)zp;
            float4 f1 = *(const float4*)(zp + 4);
            float zf[8] = {f0.x, f0.y, f0.z, f0.w, f1.x, f1.y, f1.z, f1.w};
            short8 h;
#pragma unroll
            for (int j = 0; j < 8; ++j) h[j] = (short)f2bf(zf[j]);
            Ah[s][t] = h;
        }
    }

    float track[4][4];   // PASS1: running max of acc; PASS2: limit2 = -0.5*(rowmin+MARGIN)
#pragma unroll
    for (int s = 0; s < 4; ++s)
#pragma unroll
        for (int r = 0; r < 4; ++r) {
            track[s][r] = (PASS == 1)
                ? -3.4e38f
                : -0.5f * (keyinv(rowmin[row0 + s * 16 + lgrp * 4 + r]) + MARGIN);
        }

    __syncthreads();

    const int swz = lrow & 7;
#pragma unroll 2
    for (int kt = 0; kt < KC_CH / 32; ++kt) {   // 8 iters x 32 codes
        short8 B0[2], B1[2];
        float  e2[2];
#pragma unroll
        for (int u = 0; u < 2; ++u) {
            const int c = kt * 32 + u * 16 + lrow;
            B0[u] = *(const short8*)&lds_b[c * 64 + ((lgrp ^ swz) << 3)];
            B1[u] = *(const short8*)&lds_b[c * 64 + (((lgrp + 4) ^ swz) << 3)];
            e2[u] = lds_e2[c];
        }
#pragma unroll
        for (int s = 0; s < 4; ++s) {
#pragma unroll
            for (int u = 0; u < 2; ++u) {
                f32x4 acc = {e2[u], e2[u], e2[u], e2[u]};   // acc = dot - ee/2
                acc = __builtin_amdgcn_mfma_f32_16x16x32_bf16(Ah[s][0], B0[u], acc, 0, 0, 0);
                acc = __builtin_amdgcn_mfma_f32_16x16x32_bf16(Ah[s][1], B1[u], acc, 0, 0, 0);
#pragma unroll
                for (int r = 0; r < 4; ++r) {
                    if (PASS == 1) {
                        track[s][r] = fmaxf(track[s][r], acc[r]);
                    } else {
                        if (acc[r] > track[s][r]) {   // s=-2acc < rowmin+MARGIN
                            int row = row0 + s * 16 + lgrp * 4 + r;
                            unsigned slot = atomicAdd(&cnt[row], 1u);
                            if (slot < (unsigned)CAND_CAP)
                                cand[(size_t)row * CAND_CAP + slot] =
                                    kbase + kt * 32 + u * 16 + lrow;
                        }
                    }
                }
            }
        }
    }

    if (PASS == 1) {
#pragma unroll
        for (int s = 0; s < 4; ++s)
#pragma unroll
            for (int r = 0; r < 4; ++r) {
                float v = track[s][r];
                v = fmaxf(v, __shfl_xor(v, 1));
                v = fmaxf(v, __shfl_xor(v, 2));
                v = fmaxf(v, __shfl_xor(v, 4));
                v = fmaxf(v, __shfl_xor(v, 8));
                if (lrow == 0)
                    atomicMin(&rowmin[row0 + s * 16 + lgrp * 4 + r], keyf(-2.0f * v));
            }
    }
}

// ---- exact refine: reference-exact fp32 d for candidates; min + first-index.
__global__ void k_refine(const float* __restrict__ z, const float* __restrict__ emb,
                         const float* __restrict__ ee, const unsigned* __restrict__ cnt,
                         const int* __restrict__ cand, unsigned long long* __restrict__ best)
{
    int row = blockIdx.x * 256 + threadIdx.x;
    const float4* zp = (const float4*)(z + (size_t)row * D_DIM);

    float s0 = 0.f, s1 = 0.f, s2 = 0.f, s3 = 0.f;
#pragma unroll
    for (int i = 0; i < 16; ++i) {
        float4 v = zp[i];
        s0 = fmaf(v.x, v.x, s0);
        s1 = fmaf(v.y, v.y, s1);
        s2 = fmaf(v.z, v.z, s2);
        s3 = fmaf(v.w, v.w, s3);
    }
    const float zz = (s0 + s1) + (s2 + s3);

    int c = (int)cnt[row];
    if (c > CAND_CAP) c = CAND_CAP;
    unsigned long long bk = 0xFFFFFFFFFFFFFFFFull;
    for (int i = 0; i < c; ++i) {
        int k = cand[(size_t)row * CAND_CAP + i];
        const float4* ep = (const float4*)(emb + (size_t)k * D_DIM);
        float d0 = 0.f, d1 = 0.f, d2 = 0.f, d3 = 0.f;
#pragma unroll
        for (int j = 0; j < 16; ++j) {
            float4 zv = zp[j];
            float4 ev = ep[j];
            d0 = fmaf(zv.x, ev.x, d0);
            d1 = fmaf(zv.y, ev.y, d1);
            d2 = fmaf(zv.z, ev.z, d2);
            d3 = fmaf(zv.w, ev.w, d3);
        }
        float dot = (d0 + d1) + (d2 + d3);
        float dv  = fmaf(-2.0f, dot, zz + ee[k]);   // exact r1-verified formula
        unsigned long long key =
            ((unsigned long long)__float_as_uint(dv) << 32) | (unsigned)k;
        bk = (key < bk) ? key : bk;
    }
    best[row] = bk;
}

// ---- fallback argmin (exact r2 kernel, proven passing) ----
#define NCHUNK_FB 16
#define KC_FB     (K_EMB / NCHUNK_FB)
__global__ __launch_bounds__(256) void k_argmin_fb(
    const float* __restrict__ z, const float* __restrict__ emb,
    const float* __restrict__ ee, unsigned long long* __restrict__ best)
{
    const int n  = blockIdx.x * 256 + threadIdx.x;
    const int c  = blockIdx.y;
    const int k0 = c * KC_FB;

    float4 zr[16];
    const float4* zp = (const float4*)(z + (size_t)n * D_DIM);
#pragma unroll
    for (int i = 0; i < 16; ++i) zr[i] = zp[i];

    float s0 = 0.f, s1 = 0.f, s2 = 0.f, s3 = 0.f;
#pragma unroll
    for (int i = 0; i < 16; ++i) {
        s0 = fmaf(zr[i].x, zr[i].x, s0);
        s1 = fmaf(zr[i].y, zr[i].y, s1);
        s2 = fmaf(zr[i].z, zr[i].z, s2);
        s3 = fmaf(zr[i].w, zr[i].w, s3);
    }
    const float zz = (s0 + s1) + (s2 + s3);

    const float4* ep  = (const float4*)(emb + (size_t)k0 * D_DIM);
    const float*  eep = ee + k0;

    float bestv = 3.4e38f;
    int   bi    = 0;
#pragma unroll 2
    for (int kk = 0; kk < KC_FB; ++kk) {
        float d0 = 0.f, d1 = 0.f, d2 = 0.f, d3 = 0.f;
#pragma unroll
        for (int i = 0; i < 16; ++i) {
            float4 ev = ep[kk * 16 + i];
            d0 = fmaf(zr[i].x, ev.x, d0);
            d1 = fmaf(zr[i].y, ev.y, d1);
            d2 = fmaf(zr[i].z, ev.z, d2);
            d3 = fmaf(zr[i].w, ev.w, d3);
        }
        float dot = (d0 + d1) + (d2 + d3);
        float dv = fmaf(-2.0f, dot, zz + eep[kk]);
        if (dv < bestv) { bestv = dv; bi = kk; }
    }
    unsigned long long key =
        ((unsigned long long)__float_as_uint(bestv) << 32) | (unsigned)(k0 + bi);
    atomicMin(best + n, key);
}

// ---- shared epilogue kernels (verified r1-r8) ----
__global__ void k_finish(const unsigned long long* __restrict__ best,
                         int* __restrict__ idxbuf, float* __restrict__ oidx)
{
    int n = blockIdx.x * 256 + threadIdx.x;
    int bi = (int)(best[n] & 0xFFFFFFFFull);
    idxbuf[n] = bi;
    oidx[n]   = (float)bi;
}

__global__ void k_scatter(const float* __restrict__ z, const float* __restrict__ emb,
                          const int* __restrict__ idxbuf, float* __restrict__ out_zq,
                          float* __restrict__ counts, float* __restrict__ dw,
                          float* __restrict__ lossacc)
{
    int t = blockIdx.x * 256 + threadIdx.x;
    float acc = 0.f;
#pragma unroll
    for (int i = 0; i < 16; ++i) {
        int e = t + i * 131072;
        int nrow = e >> 6, d = e & 63;
        int k = idxbuf[nrow];
        float zv  = z[e];
        float evv = emb[(size_t)k * D_DIM + d];
        out_zq[e] = zv + (evv - zv);
        float diff = zv - evv;
        acc = fmaf(diff, diff, acc);
        atomicAdd(&dw[(size_t)k * D_DIM + d], zv);
        if (d == 0) atomicAdd(&counts[k], 1.0f);
    }
    __shared__ float red[256];
    red[threadIdx.x] = acc;
    __syncthreads();
    for (int s = 128; s > 0; s >>= 1) {
        if (threadIdx.x < s) red[threadIdx.x] += red[threadIdx.x + s];
        __syncthreads();
    }
    if (threadIdx.x == 0) atomicAdd(lossacc, red[0]);
}

__global__ void k_stats(const float* __restrict__ ema_cs, const float* __restrict__ counts,
                        const float* __restrict__ lossacc, float* __restrict__ out_cs,
                        float* __restrict__ out_loss, float* __restrict__ ws_n)
{
    __shared__ float red[256];
    float local = 0.f;
    for (int k = threadIdx.x; k < K_EMB; k += 256) {
        float v = 0.99f * ema_cs[k] + 0.01f * counts[k];
        out_cs[k] = v;
        local += v;
    }
    red[threadIdx.x] = local;
    __syncthreads();
    for (int s = 128; s > 0; s >>= 1) {
        if (threadIdx.x < s) red[threadIdx.x] += red[threadIdx.x + s];
        __syncthreads();
    }
    if (threadIdx.x == 0) {
        ws_n[0] = red[0];
        out_loss[0] = 0.25f * (lossacc[0] / 2097152.0f);
    }
}

__global__ void k_emb(const float* __restrict__ ema_w, const float* __restrict__ dw,
                      const float* __restrict__ out_cs, const float* __restrict__ ws_n,
                      float* __restrict__ out_emb, float* __restrict__ out_emaw)
{
    int e = blockIdx.x * 256 + threadIdx.x;
    int k = e >> 6;
    float nv = ws_n[0];
    float w  = 0.99f * ema_w[e] + 0.01f * dw[e];
    out_emaw[e] = w;
    float cs = (out_cs[k] + 1e-5f) / (nv + 0.04096f) * nv;
    out_emb[e] = w / cs;
}

extern "C" void kernel_launch(void* const* d_in, const int* in_sizes, int n_in,
                              void* d_out, int out_size, void* d_ws, size_t ws_size,
                              hipStream_t stream)
{
    const float* z      = (const float*)d_in[0];
    const float* emb    = (const float*)d_in[1];
    const float* ema_cs = (const float*)d_in[2];
    const float* ema_w  = (const float*)d_in[3];

    float* out   = (float*)d_out;
    float* o_zq  = out + O_ZQ;
    float* o_idx = out + O_IDX;
    float* o_ls  = out + O_LOSS;
    float* o_em  = out + O_EMB;
    float* o_cs  = out + O_CS;
    float* o_ew  = out + O_EMAW;

    float* w      = (float*)d_ws;
    float* ee     = w + WS_EE;
    unsigned long long* best = (unsigned long long*)(w + WS_BEST);
    int*   idxbuf = (int*)(w + WS_IDX);
    float* counts = w + WS_COUNTS;
    float* dw     = w + WS_DW;
    float* lossa  = w + WS_LOSS;
    float* ws_n   = w + WS_N;

    hipMemsetAsync((char*)d_ws + (size_t)WS_BEST * 4, 0xFF, (size_t)N_ROWS * 8, stream);
    hipMemsetAsync((char*)d_ws + (size_t)WS_COUNTS * 4, 0,
                   (size_t)(WS_N + 1 - WS_COUNTS) * 4, stream);

    if (ws_size >= WS_NEED_BYTES) {
        unsigned short* bhi = (unsigned short*)(w + F_BHI);
        unsigned* rowmin    = (unsigned*)(w + F_ROWMIN);
        unsigned* cnt       = (unsigned*)(w + F_CNT);
        int*      cand      = (int*)(w + F_CAND);

        hipMemsetAsync((char*)d_ws + (size_t)F_ROWMIN * 4, 0xFF, (size_t)N_ROWS * 4, stream);
        hipMemsetAsync((char*)d_ws + (size_t)F_CNT * 4, 0, (size_t)N_ROWS * 4, stream);

        k_prep<<<K_EMB / 256, 256, 0, stream>>>(emb, ee, bhi);
        k_mfma_pass<1><<<dim3(N_ROWS / 256, NCHUNKY), 256, 0, stream>>>(z, bhi, ee,
                                                                        rowmin, cnt, cand);
        k_mfma_pass<2><<<dim3(N_ROWS / 256, NCHUNKY), 256, 0, stream>>>(z, bhi, ee,
                                                                        rowmin, cnt, cand);
        k_refine<<<N_ROWS / 256, 256, 0, stream>>>(z, emb, ee, cnt, cand, best);
    } else {
        k_ee<<<K_EMB / 256, 256, 0, stream>>>(emb, ee);
        k_argmin_fb<<<dim3(N_ROWS / 256, NCHUNK_FB), 256, 0, stream>>>(z, emb, ee, best);
    }

    k_finish<<<N_ROWS / 256, 256, 0, stream>>>(best, idxbuf, o_idx);
    k_scatter<<<512, 256, 0, stream>>>(z, emb, idxbuf, o_zq, counts, dw, lossa);
    k_stats<<<1, 256, 0, stream>>>(ema_cs, counts, lossa, o_cs, o_ls, ws_n);
    k_emb<<<(K_EMB * D_DIM) / 256, 256, 0, stream>>>(ema_w, dw, o_cs, ws_n, o_em, o_ew);
}

// Round 10
// 159.716 us; speedup vs baseline: 1.8272x; 1.0047x over previous
//
#include <hip/hip_runtime.h>

#define N_ROWS 32768
#define K_EMB  4096
#define D_DIM  64
#define MARGIN 5e-4f
#define CAND_CAP 16
#define NQ      4                  // k-quarters (grid.y)
#define KC_CH   256                // codes staged per chunk
#define CH_PER  (K_EMB / NQ / KC_CH)   // 4 chunks per block sweep

// ---- ws layout (float offsets)
#define WS_EE     0
#define WS_BEST   4096      // 32768 x u64 at byte 16384
#define WS_IDX    69632
#define WS_COUNTS 102400
#define WS_DW     106496
#define WS_LOSS   368640
#define WS_N      368641
#define F_BHI     368644    // 4096*64 bf16
#define F_BLO     499716    // (unused; kept so layout/NEED_BYTES is stable)
#define F_ROWMIN  630788    // 32768 u32
#define F_CNT     663556    // 32768 u32
#define F_CAND    696324    // 32768*16 i32
#define WS_NEED_BYTES ((size_t)(696324 + 32768 * CAND_CAP) * 4)

// ---- out layout (float offsets)
#define O_ZQ    0
#define O_IDX   2097152
#define O_LOSS  2129920
#define O_EMB   2129921
#define O_CS    2392065
#define O_EMAW  2396161

typedef __attribute__((ext_vector_type(8))) short short8;
typedef __attribute__((ext_vector_type(4))) float f32x4;

__device__ __forceinline__ unsigned short f2bf(float f) {
    unsigned u = __float_as_uint(f);
    unsigned r = (u + 0x7FFFu + ((u >> 16) & 1u)) >> 16;   // RNE
    return (unsigned short)r;
}
__device__ __forceinline__ unsigned keyf(float f) {
    unsigned u = __float_as_uint(f);
    return (u & 0x80000000u) ? ~u : (u | 0x80000000u);
}
__device__ __forceinline__ float keyinv(unsigned k) {
    unsigned u = (k & 0x80000000u) ? (k ^ 0x80000000u) : ~k;
    return __uint_as_float(u);
}

// ---- ee only (exact r1 order) — used by the fallback path
__global__ void k_ee(const float* __restrict__ emb, float* __restrict__ ee) {
    int k = blockIdx.x * 256 + threadIdx.x;
    const float4* e4 = (const float4*)(emb + (size_t)k * D_DIM);
    float s0 = 0.f, s1 = 0.f, s2 = 0.f, s3 = 0.f;
#pragma unroll
    for (int i = 0; i < 16; ++i) {
        float4 v = e4[i];
        s0 = fmaf(v.x, v.x, s0);
        s1 = fmaf(v.y, v.y, s1);
        s2 = fmaf(v.z, v.z, s2);
        s3 = fmaf(v.w, v.w, s3);
    }
    ee[k] = (s0 + s1) + (s2 + s3);
}

// ---- prep: ee (exact r1 order) + bf16 hi split of emb
__global__ void k_prep(const float* __restrict__ emb, float* __restrict__ ee,
                       unsigned short* __restrict__ bhi)
{
    int k = blockIdx.x * 256 + threadIdx.x;
    const float4* e4 = (const float4*)(emb + (size_t)k * D_DIM);
    float s0 = 0.f, s1 = 0.f, s2 = 0.f, s3 = 0.f;
    unsigned short* bh = bhi + (size_t)k * D_DIM;
#pragma unroll
    for (int i = 0; i < 16; ++i) {
        float4 v = e4[i];
        s0 = fmaf(v.x, v.x, s0);
        s1 = fmaf(v.y, v.y, s1);
        s2 = fmaf(v.z, v.z, s2);
        s3 = fmaf(v.w, v.w, s3);
        bh[4 * i + 0] = f2bf(v.x);
        bh[4 * i + 1] = f2bf(v.y);
        bh[4 * i + 2] = f2bf(v.z);
        bh[4 * i + 3] = f2bf(v.w);
    }
    ee[k] = (s0 + s1) + (s2 + s3);
}

// ---- hi-only MFMA distance scan, LDS-staged B, chunk loop in-kernel.
// r9 post-mortem: per-pass cost tracked total global-load INSTRUCTIONS
// (A-frag build 16/wave + staging 9/thread, re-run per (row,chunk) pair =
// ~13M/pass). This round: grid (128 rows x 4 k-quarters), each block loops
// 4 chunks -> A-build amortized 4x, loads/pass ~3.3M. bounds(256,2) gives
// the allocator VGPR headroom to keep the A-loads in flight (r5 lesson:
// budget must exceed need; need ~130 < 256).
// Math identical to r8/r9 (verified): acc = dot - ee/2; PASS1 max-track;
// PASS2 collect acc > -0.5*(rowmin+MARGIN); refine recomputes exact fp32.
template <int PASS>
__global__ __launch_bounds__(256, 2) void k_mfma_pass(
    const float* __restrict__ z, const unsigned short* __restrict__ bhi,
    const float* __restrict__ ee,
    unsigned* __restrict__ rowmin, unsigned* __restrict__ cnt, int* __restrict__ cand)
{
    __shared__ unsigned short lds_b[KC_CH * 64];  // 32 KB, swizzled
    __shared__ float lds_e2[KC_CH];               // -ee/2, 1 KB

    const int tid  = threadIdx.x;
    const int lane = tid & 63, wave = tid >> 6;
    const int lrow = lane & 15, lgrp = lane >> 4;
    const int row0   = blockIdx.x * 256 + wave * 64;   // this wave: 64 rows
    const int kquart = blockIdx.y * (K_EMB / NQ);      // this block: 1024 codes

    // ---- A fragments (hi only), built ONCE per block sweep: 32 VGPRs data,
    // 16 float4 loads the compiler can now keep in flight.
    short8 Ah[4][2];
#pragma unroll
    for (int s = 0; s < 4; ++s) {
#pragma unroll
        for (int t = 0; t < 2; ++t) {
            const float* zp = z + (size_t)(row0 + s * 16 + lrow) * D_DIM + t * 32 + lgrp * 8;
            float4 f0 = *(const float4*)zp;
            float4 f1 = *(const float4*)(zp + 4);
            float zf[8] = {f0.x, f0.y, f0.z, f0.w, f1.x, f1.y, f1.z, f1.w};
            short8 h;
#pragma unroll
            for (int j = 0; j < 8; ++j) h[j] = (short)f2bf(zf[j]);
            Ah[s][t] = h;
        }
    }

    float track[4][4];   // PASS1: running max of acc; PASS2: limit2
#pragma unroll
    for (int s = 0; s < 4; ++s)
#pragma unroll
        for (int r = 0; r < 4; ++r) {
            track[s][r] = (PASS == 1)
                ? -3.4e38f
                : -0.5f * (keyinv(rowmin[row0 + s * 16 + lgrp * 4 + r]) + MARGIN);
        }

    const int swz = lrow & 7;

    for (int ch = 0; ch < CH_PER; ++ch) {
        const int kbase = kquart + ch * KC_CH;

        __syncthreads();   // prior chunk's readers done before overwrite
        // ---- stage B chunk (coalesced; swizzled ds_write) + -ee/2
        {
            const short8* gsrc = (const short8*)(bhi + (size_t)kbase * D_DIM);
            short8 v[8];
#pragma unroll
            for (int j = 0; j < 8; ++j) v[j] = gsrc[tid + j * 256];
            const int s_slot = tid & 7, c0 = tid >> 3;
#pragma unroll
            for (int j = 0; j < 8; ++j) {
                int c = c0 + j * 32;
                *(short8*)&lds_b[c * 64 + ((s_slot ^ (c & 7)) << 3)] = v[j];
            }
            lds_e2[tid & (KC_CH - 1)] = -0.5f * ee[kbase + (tid & (KC_CH - 1))];
        }
        __syncthreads();

#pragma unroll 2
        for (int kt = 0; kt < KC_CH / 32; ++kt) {   // 8 iters x 32 codes
            short8 B0[2], B1[2];
            float  e2[2];
#pragma unroll
            for (int u = 0; u < 2; ++u) {
                const int c = kt * 32 + u * 16 + lrow;
                B0[u] = *(const short8*)&lds_b[c * 64 + ((lgrp ^ swz) << 3)];
                B1[u] = *(const short8*)&lds_b[c * 64 + (((lgrp + 4) ^ swz) << 3)];
                e2[u] = lds_e2[c];
            }
#pragma unroll
            for (int s = 0; s < 4; ++s) {
#pragma unroll
                for (int u = 0; u < 2; ++u) {
                    f32x4 acc = {e2[u], e2[u], e2[u], e2[u]};   // acc = dot - ee/2
                    acc = __builtin_amdgcn_mfma_f32_16x16x32_bf16(Ah[s][0], B0[u], acc, 0, 0, 0);
                    acc = __builtin_amdgcn_mfma_f32_16x16x32_bf16(Ah[s][1], B1[u], acc, 0, 0, 0);
#pragma unroll
                    for (int r = 0; r < 4; ++r) {
                        if (PASS == 1) {
                            track[s][r] = fmaxf(track[s][r], acc[r]);
                        } else {
                            if (acc[r] > track[s][r]) {   // s=-2acc < rowmin+MARGIN
                                int row = row0 + s * 16 + lgrp * 4 + r;
                                unsigned slot = atomicAdd(&cnt[row], 1u);
                                if (slot < (unsigned)CAND_CAP)
                                    cand[(size_t)row * CAND_CAP + slot] =
                                        kbase + kt * 32 + u * 16 + lrow;
                            }
                        }
                    }
                }
            }
        }
    }

    if (PASS == 1) {
#pragma unroll
        for (int s = 0; s < 4; ++s)
#pragma unroll
            for (int r = 0; r < 4; ++r) {
                float v = track[s][r];
                v = fmaxf(v, __shfl_xor(v, 1));
                v = fmaxf(v, __shfl_xor(v, 2));
                v = fmaxf(v, __shfl_xor(v, 4));
                v = fmaxf(v, __shfl_xor(v, 8));
                if (lrow == 0)
                    atomicMin(&rowmin[row0 + s * 16 + lgrp * 4 + r], keyf(-2.0f * v));
            }
    }
}

// ---- exact refine: reference-exact fp32 d for candidates; min + first-index.
__global__ void k_refine(const float* __restrict__ z, const float* __restrict__ emb,
                         const float* __restrict__ ee, const unsigned* __restrict__ cnt,
                         const int* __restrict__ cand, unsigned long long* __restrict__ best)
{
    int row = blockIdx.x * 256 + threadIdx.x;
    const float4* zp = (const float4*)(z + (size_t)row * D_DIM);

    float s0 = 0.f, s1 = 0.f, s2 = 0.f, s3 = 0.f;
#pragma unroll
    for (int i = 0; i < 16; ++i) {
        float4 v = zp[i];
        s0 = fmaf(v.x, v.x, s0);
        s1 = fmaf(v.y, v.y, s1);
        s2 = fmaf(v.z, v.z, s2);
        s3 = fmaf(v.w, v.w, s3);
    }
    const float zz = (s0 + s1) + (s2 + s3);

    int c = (int)cnt[row];
    if (c > CAND_CAP) c = CAND_CAP;
    unsigned long long bk = 0xFFFFFFFFFFFFFFFFull;
    for (int i = 0; i < c; ++i) {
        int k = cand[(size_t)row * CAND_CAP + i];
        const float4* ep = (const float4*)(emb + (size_t)k * D_DIM);
        float d0 = 0.f, d1 = 0.f, d2 = 0.f, d3 = 0.f;
#pragma unroll
        for (int j = 0; j < 16; ++j) {
            float4 zv = zp[j];
            float4 ev = ep[j];
            d0 = fmaf(zv.x, ev.x, d0);
            d1 = fmaf(zv.y, ev.y, d1);
            d2 = fmaf(zv.z, ev.z, d2);
            d3 = fmaf(zv.w, ev.w, d3);
        }
        float dot = (d0 + d1) + (d2 + d3);
        float dv  = fmaf(-2.0f, dot, zz + ee[k]);   // exact r1-verified formula
        unsigned long long key =
            ((unsigned long long)__float_as_uint(dv) << 32) | (unsigned)k;
        bk = (key < bk) ? key : bk;
    }
    best[row] = bk;
}

// ---- fallback argmin (exact r2 kernel, proven passing) ----
#define NCHUNK_FB 16
#define KC_FB     (K_EMB / NCHUNK_FB)
__global__ __launch_bounds__(256) void k_argmin_fb(
    const float* __restrict__ z, const float* __restrict__ emb,
    const float* __restrict__ ee, unsigned long long* __restrict__ best)
{
    const int n  = blockIdx.x * 256 + threadIdx.x;
    const int c  = blockIdx.y;
    const int k0 = c * KC_FB;

    float4 zr[16];
    const float4* zp = (const float4*)(z + (size_t)n * D_DIM);
#pragma unroll
    for (int i = 0; i < 16; ++i) zr[i] = zp[i];

    float s0 = 0.f, s1 = 0.f, s2 = 0.f, s3 = 0.f;
#pragma unroll
    for (int i = 0; i < 16; ++i) {
        s0 = fmaf(zr[i].x, zr[i].x, s0);
        s1 = fmaf(zr[i].y, zr[i].y, s1);
        s2 = fmaf(zr[i].z, zr[i].z, s2);
        s3 = fmaf(zr[i].w, zr[i].w, s3);
    }
    const float zz = (s0 + s1) + (s2 + s3);

    const float4* ep  = (const float4*)(emb + (size_t)k0 * D_DIM);
    const float*  eep = ee + k0;

    float bestv = 3.4e38f;
    int   bi    = 0;
#pragma unroll 2
    for (int kk = 0; kk < KC_FB; ++kk) {
        float d0 = 0.f, d1 = 0.f, d2 = 0.f, d3 = 0.f;
#pragma unroll
        for (int i = 0; i < 16; ++i) {
            float4 ev = ep[kk * 16 + i];
            d0 = fmaf(zr[i].x, ev.x, d0);
            d1 = fmaf(zr[i].y, ev.y, d1);
            d2 = fmaf(zr[i].z, ev.z, d2);
            d3 = fmaf(zr[i].w, ev.w, d3);
        }
        float dot = (d0 + d1) + (d2 + d3);
        float dv = fmaf(-2.0f, dot, zz + eep[kk]);
        if (dv < bestv) { bestv = dv; bi = kk; }
    }
    unsigned long long key =
        ((unsigned long long)__float_as_uint(bestv) << 32) | (unsigned)(k0 + bi);
    atomicMin(best + n, key);
}

// ---- shared epilogue kernels (verified r1-r9) ----
__global__ void k_finish(const unsigned long long* __restrict__ best,
                         int* __restrict__ idxbuf, float* __restrict__ oidx)
{
    int n = blockIdx.x * 256 + threadIdx.x;
    int bi = (int)(best[n] & 0xFFFFFFFFull);
    idxbuf[n] = bi;
    oidx[n]   = (float)bi;
}

__global__ void k_scatter(const float* __restrict__ z, const float* __restrict__ emb,
                          const int* __restrict__ idxbuf, float* __restrict__ out_zq,
                          float* __restrict__ counts, float* __restrict__ dw,
                          float* __restrict__ lossacc)
{
    int t = blockIdx.x * 256 + threadIdx.x;
    float acc = 0.f;
#pragma unroll
    for (int i = 0; i < 16; ++i) {
        int e = t + i * 131072;
        int nrow = e >> 6, d = e & 63;
        int k = idxbuf[nrow];
        float zv  = z[e];
        float evv = emb[(size_t)k * D_DIM + d];
        out_zq[e] = zv + (evv - zv);
        float diff = zv - evv;
        acc = fmaf(diff, diff, acc);
        atomicAdd(&dw[(size_t)k * D_DIM + d], zv);
        if (d == 0) atomicAdd(&counts[k], 1.0f);
    }
    __shared__ float red[256];
    red[threadIdx.x] = acc;
    __syncthreads();
    for (int s = 128; s > 0; s >>= 1) {
        if (threadIdx.x < s) red[threadIdx.x] += red[threadIdx.x + s];
        __syncthreads();
    }
    if (threadIdx.x == 0) atomicAdd(lossacc, red[0]);
}

__global__ void k_stats(const float* __restrict__ ema_cs, const float* __restrict__ counts,
                        const float* __restrict__ lossacc, float* __restrict__ out_cs,
                        float* __restrict__ out_loss, float* __restrict__ ws_n)
{
    __shared__ float red[256];
    float local = 0.f;
    for (int k = threadIdx.x; k < K_EMB; k += 256) {
        float v = 0.99f * ema_cs[k] + 0.01f * counts[k];
        out_cs[k] = v;
        local += v;
    }
    red[threadIdx.x] = local;
    __syncthreads();
    for (int s = 128; s > 0; s >>= 1) {
        if (threadIdx.x < s) red[threadIdx.x] += red[threadIdx.x + s];
        __syncthreads();
    }
    if (threadIdx.x == 0) {
        ws_n[0] = red[0];
        out_loss[0] = 0.25f * (lossacc[0] / 2097152.0f);
    }
}

__global__ void k_emb(const float* __restrict__ ema_w, const float* __restrict__ dw,
                      const float* __restrict__ out_cs, const float* __restrict__ ws_n,
                      float* __restrict__ out_emb, float* __restrict__ out_emaw)
{
    int e = blockIdx.x * 256 + threadIdx.x;
    int k = e >> 6;
    float nv = ws_n[0];
    float w  = 0.99f * ema_w[e] + 0.01f * dw[e];
    out_emaw[e] = w;
    float cs = (out_cs[k] + 1e-5f) / (nv + 0.04096f) * nv;
    out_emb[e] = w / cs;
}

extern "C" void kernel_launch(void* const* d_in, const int* in_sizes, int n_in,
                              void* d_out, int out_size, void* d_ws, size_t ws_size,
                              hipStream_t stream)
{
    const float* z      = (const float*)d_in[0];
    const float* emb    = (const float*)d_in[1];
    const float* ema_cs = (const float*)d_in[2];
    const float* ema_w  = (const float*)d_in[3];

    float* out   = (float*)d_out;
    float* o_zq  = out + O_ZQ;
    float* o_idx = out + O_IDX;
    float* o_ls  = out + O_LOSS;
    float* o_em  = out + O_EMB;
    float* o_cs  = out + O_CS;
    float* o_ew  = out + O_EMAW;

    float* w      = (float*)d_ws;
    float* ee     = w + WS_EE;
    unsigned long long* best = (unsigned long long*)(w + WS_BEST);
    int*   idxbuf = (int*)(w + WS_IDX);
    float* counts = w + WS_COUNTS;
    float* dw     = w + WS_DW;
    float* lossa  = w + WS_LOSS;
    float* ws_n   = w + WS_N;

    hipMemsetAsync((char*)d_ws + (size_t)WS_BEST * 4, 0xFF, (size_t)N_ROWS * 8, stream);
    hipMemsetAsync((char*)d_ws + (size_t)WS_COUNTS * 4, 0,
                   (size_t)(WS_N + 1 - WS_COUNTS) * 4, stream);

    if (ws_size >= WS_NEED_BYTES) {
        unsigned short* bhi = (unsigned short*)(w + F_BHI);
        unsigned* rowmin    = (unsigned*)(w + F_ROWMIN);
        unsigned* cnt       = (unsigned*)(w + F_CNT);
        int*      cand      = (int*)(w + F_CAND);

        hipMemsetAsync((char*)d_ws + (size_t)F_ROWMIN * 4, 0xFF, (size_t)N_ROWS * 4, stream);
        hipMemsetAsync((char*)d_ws + (size_t)F_CNT * 4, 0, (size_t)N_ROWS * 4, stream);

        k_prep<<<K_EMB / 256, 256, 0, stream>>>(emb, ee, bhi);
        k_mfma_pass<1><<<dim3(N_ROWS / 256, NQ), 256, 0, stream>>>(z, bhi, ee,
                                                                   rowmin, cnt, cand);
        k_mfma_pass<2><<<dim3(N_ROWS / 256, NQ), 256, 0, stream>>>(z, bhi, ee,
                                                                   rowmin, cnt, cand);
        k_refine<<<N_ROWS / 256, 256, 0, stream>>>(z, emb, ee, cnt, cand, best);
    } else {
        k_ee<<<K_EMB / 256, 256, 0, stream>>>(emb, ee);
        k_argmin_fb<<<dim3(N_ROWS / 256, NCHUNK_FB), 256, 0, stream>>>(z, emb, ee, best);
    }

    k_finish<<<N_ROWS / 256, 256, 0, stream>>>(best, idxbuf, o_idx);
    k_scatter<<<512, 256, 0, stream>>>(z, emb, idxbuf, o_zq, counts, dw, lossa);
    k_stats<<<1, 256, 0, stream>>>(ema_cs, counts, lossa, o_cs, o_ls, ws_n);
    k_emb<<<(K_EMB * D_DIM) / 256, 256, 0, stream>>>(ema_w, dw, o_cs, ws_n, o_em, o_ew);
}